// Round 6
// baseline (438.630 us; speedup 1.0000x reference)
//
#include <hip/hip_runtime.h>
#include <hip/hip_bf16.h>
#include <stdint.h>

// R14: attn rewritten around 32x32x16 MFMA. Per tile: QK^T (16 MFMA) ->
// in-register softmax (lane owns q=lane&31; one shfl_xor(32) completes
// row stats) -> P packed to bf16 B-frags in-register via shfl_xor(32)
// exchange (no P LDS round-trip) -> PV (16 MFMA). K/V double-buffered in
// LDS with XOR-bit4-6 swizzle: K staged via global_load_lds with
// pre-swizzled per-lane SOURCE (rule #21), V^T reg-staged with swizzled
// writes. ONE barrier per tile. 4 waves x 32q = 128 q/block; 512 blocks
// = 2/CU, balanced-pair decode. defer-max + setprio kept.
// GEMMs/converts identical to R13.

typedef __bf16 bf16x8 __attribute__((ext_vector_type(8)));
typedef float f32x4 __attribute__((ext_vector_type(4)));
typedef float f32x16 __attribute__((ext_vector_type(16)));
typedef unsigned short u16x8 __attribute__((ext_vector_type(8)));
typedef unsigned short u16x4 __attribute__((ext_vector_type(4)));
typedef unsigned int u32x4v __attribute__((ext_vector_type(4)));

__device__ __forceinline__ unsigned short f2bf(float f) {
  unsigned int u = __builtin_bit_cast(unsigned int, f);
  u += 0x7fff + ((u >> 16) & 1);   // RNE; values are finite
  return (unsigned short)(u >> 16);
}
__device__ __forceinline__ float bf2f(unsigned short u) {
  return __builtin_bit_cast(float, (unsigned int)u << 16);
}

__device__ __forceinline__ u16x8 cvt8(const float* p) {
  f32x4 lo = *(const f32x4*)p;
  f32x4 hi = *(const f32x4*)(p + 4);
  u16x8 r;
#pragma unroll
  for (int j = 0; j < 4; j++) { r[j] = f2bf(lo[j]); r[4 + j] = f2bf(hi[j]); }
  return r;
}

// async 16B global->LDS copy. LDS dest is wave-uniform base; HW adds lane*16.
__device__ __forceinline__ void gload16(const void* g, void* l) {
  __builtin_amdgcn_global_load_lds(
      (const __attribute__((address_space(1))) void*)g,
      (__attribute__((address_space(3))) void*)l, 16, 0, 0);
}

// ---------------------------------------------------------------------------
// fp32 -> bf16 bulk convert. n8 = element count / 8. Memory-bound.
// ---------------------------------------------------------------------------
__global__ __launch_bounds__(256) void f32_to_bf16(
    const float* __restrict__ src, unsigned short* __restrict__ dst, int n8) {
  int i = blockIdx.x * 256 + threadIdx.x;
  const int stride = gridDim.x * 256;
  for (; i < n8; i += stride) {
    u16x8 v = cvt8(src + (size_t)i * 8);
    *(u16x8*)&dst[(size_t)i * 8] = v;
  }
}

// ---------------------------------------------------------------------------
// 128x128 GEMM (R10-proven): C[M][N] = A[M][K] @ B[N][K]^T, bf16 in.
// ---------------------------------------------------------------------------
template <bool COF32>
__global__ __launch_bounds__(256) void gemm_bf(
    const unsigned short* __restrict__ A, const unsigned short* __restrict__ B,
    void* __restrict__ Cv, int M, int N, int K) {
  __shared__ __align__(16) unsigned short Alds[128 * 32];
  __shared__ __align__(16) unsigned short Blds[128 * 32];

  const int tid  = threadIdx.x;
  const int lane = tid & 63;
  const int w    = tid >> 6;
  const int ln   = lane & 15;
  const int kq   = lane >> 4;
  const int m0 = blockIdx.y * 128;
  const int n0 = blockIdx.x * 128;
  const int m_base = (w >> 1) * 64;
  const int n_base = (w & 1) * 64;

  f32x4 acc[4][4];
#pragma unroll
  for (int i = 0; i < 4; i++)
#pragma unroll
    for (int j = 0; j < 4; j++) acc[i][j] = {0.f, 0.f, 0.f, 0.f};

  const int c0 = tid;
  const int c1 = tid + 256;
  const unsigned short* Ag0 = A + (size_t)(m0 + (c0 >> 2)) * K + (c0 & 3) * 8;
  const unsigned short* Ag1 = A + (size_t)(m0 + (c1 >> 2)) * K + (c1 & 3) * 8;
  const unsigned short* Bg0 = B + (size_t)(n0 + (c0 >> 2)) * K + (c0 & 3) * 8;
  const unsigned short* Bg1 = B + (size_t)(n0 + (c1 >> 2)) * K + (c1 & 3) * 8;
  unsigned short* lA0 = &Alds[(size_t)w * 512];
  unsigned short* lA1 = &Alds[2048 + (size_t)w * 512];
  unsigned short* lB0 = &Blds[(size_t)w * 512];
  unsigned short* lB1 = &Blds[2048 + (size_t)w * 512];

  const int nk = K >> 5;
  for (int kt = 0; kt < nk; kt++) {
    const int ko = kt * 32;
    gload16(Ag0 + ko, lA0);
    gload16(Ag1 + ko, lA1);
    gload16(Bg0 + ko, lB0);
    gload16(Bg1 + ko, lB1);
    __syncthreads();

    bf16x8 af[4], bfr[4];
#pragma unroll
    for (int i = 0; i < 4; i++)
      af[i] = *(const bf16x8*)&Alds[(m_base + i * 16 + ln) * 32 + kq * 8];
#pragma unroll
    for (int j = 0; j < 4; j++)
      bfr[j] = *(const bf16x8*)&Blds[(n_base + j * 16 + ln) * 32 + kq * 8];
#pragma unroll
    for (int i = 0; i < 4; i++)
#pragma unroll
      for (int j = 0; j < 4; j++)
        acc[i][j] = __builtin_amdgcn_mfma_f32_16x16x32_bf16(af[i], bfr[j], acc[i][j], 0, 0, 0);
    __syncthreads();
  }

#pragma unroll
  for (int i = 0; i < 4; i++) {
    const int row_base = m0 + m_base + i * 16 + kq * 4;
#pragma unroll
    for (int j = 0; j < 4; j++) {
      const int col = n0 + n_base + j * 16 + ln;
#pragma unroll
      for (int r = 0; r < 4; r++) {
        const size_t idx = (size_t)(row_base + r) * N + col;
        if (COF32) ((float*)Cv)[idx] = acc[i][j][r];
        else       ((unsigned short*)Cv)[idx] = f2bf(acc[i][j][r]);
      }
    }
  }
}

// ---------------------------------------------------------------------------
// 8-phase GEMM (R12/R13): 256x256 tile, BK=64, 512 threads, ks-half-major
// LDS with XOR-bit5 swizzle; vmcnt(4) boundary; setprio; lgkmcnt hints.
// ---------------------------------------------------------------------------
template <bool COF32>
__global__ __launch_bounds__(512, 2) void gemm8(
    const unsigned short* __restrict__ A, const unsigned short* __restrict__ B,
    void* __restrict__ Cv, int M, int N, int K) {
  __shared__ __align__(1024) unsigned short As[2][16384];
  __shared__ __align__(1024) unsigned short Bs[2][16384];

  const int tid  = threadIdx.x;
  const int lane = tid & 63;
  const int w    = tid >> 6;
  const int ln   = lane & 15;
  const int kq   = lane >> 4;
  const int wm   = w >> 2;
  const int wn   = w & 3;
  const int m0 = blockIdx.y * 256;
  const int n0 = blockIdx.x * 256;

  const int kswz = (kq * 8) ^ ((ln & 8) << 1);

  const int lx = lane ^ (((lane >> 5) & 1) << 1);
  const int srow = w * 16 + (lx >> 2);
  const int scol = (lx & 3) * 8;
  const unsigned short* Asrc = A + (size_t)(m0 + srow) * K + scol;
  const unsigned short* Bsrc = B + (size_t)(n0 + srow) * K + scol;

  f32x4 acc[8][4];
#pragma unroll
  for (int i = 0; i < 8; i++)
#pragma unroll
    for (int j = 0; j < 4; j++) acc[i][j] = {0.f, 0.f, 0.f, 0.f};

  auto stgA = [&](int buf, int t, int h) {
    const size_t off = (size_t)t * 64 + (size_t)(h * 128) * K;
    gload16(Asrc + off,      &As[buf][h * 4096 + w * 512]);
    gload16(Asrc + off + 32, &As[buf][8192 + h * 4096 + w * 512]);
  };
  auto stgB = [&](int buf, int t, int h) {
    const size_t off = (size_t)t * 64 + (size_t)(h * 128) * K;
    gload16(Bsrc + off,      &Bs[buf][h * 4096 + w * 512]);
    gload16(Bsrc + off + 32, &Bs[buf][8192 + h * 4096 + w * 512]);
  };
  auto rdA = [&](int buf, int mi, int ks) -> bf16x8 {
    return *(const bf16x8*)&As[buf][ks * 8192 + (wm * 128 + mi * 16 + ln) * 32 + kswz];
  };
  auto rdB = [&](int buf, int nj, int ks) -> bf16x8 {
    return *(const bf16x8*)&Bs[buf][ks * 8192 + (wn * 64 + nj * 16 + ln) * 32 + kswz];
  };

  const int NT = K >> 6;

  stgA(0, 0, 0); stgA(0, 0, 1); stgB(0, 0, 0); stgB(0, 0, 1);
  stgA(1, 1, 0); stgA(1, 1, 1);
  asm volatile("s_waitcnt vmcnt(4)" ::: "memory");
  __builtin_amdgcn_s_barrier();

  bf16x8 a0[4][2], a1[4][2], b01[2][2], b23[2][2];

#pragma unroll 2
  for (int t = 0; t < NT; t++) {
    const int cur = t & 1, nxt = cur ^ 1;

#pragma unroll
    for (int i = 0; i < 4; i++) { a0[i][0] = rdA(cur, i, 0); a0[i][1] = rdA(cur, i, 1); }
#pragma unroll
    for (int j = 0; j < 2; j++) { b01[j][0] = rdB(cur, j, 0); b01[j][1] = rdB(cur, j, 1); }
    if (t + 1 < NT) stgB(nxt, t + 1, 0);
    asm volatile("s_waitcnt lgkmcnt(8)" ::: "memory");
    __builtin_amdgcn_s_barrier();
    asm volatile("s_waitcnt lgkmcnt(0)" ::: "memory");
    __builtin_amdgcn_sched_barrier(0);
    __builtin_amdgcn_s_setprio(1);
#pragma unroll
    for (int i = 0; i < 4; i++)
#pragma unroll
      for (int j = 0; j < 2; j++) {
        acc[i][j] = __builtin_amdgcn_mfma_f32_16x16x32_bf16(a0[i][0], b01[j][0], acc[i][j], 0, 0, 0);
        acc[i][j] = __builtin_amdgcn_mfma_f32_16x16x32_bf16(a0[i][1], b01[j][1], acc[i][j], 0, 0, 0);
      }
    __builtin_amdgcn_s_setprio(0);
    __builtin_amdgcn_s_barrier();

#pragma unroll
    for (int j = 0; j < 2; j++) { b23[j][0] = rdB(cur, 2 + j, 0); b23[j][1] = rdB(cur, 2 + j, 1); }
    if (t + 1 < NT) stgB(nxt, t + 1, 1);
    __builtin_amdgcn_s_barrier();
    asm volatile("s_waitcnt lgkmcnt(0)" ::: "memory");
    __builtin_amdgcn_sched_barrier(0);
    __builtin_amdgcn_s_setprio(1);
#pragma unroll
    for (int i = 0; i < 4; i++)
#pragma unroll
      for (int j = 0; j < 2; j++) {
        acc[i][2 + j] = __builtin_amdgcn_mfma_f32_16x16x32_bf16(a0[i][0], b23[j][0], acc[i][2 + j], 0, 0, 0);
        acc[i][2 + j] = __builtin_amdgcn_mfma_f32_16x16x32_bf16(a0[i][1], b23[j][1], acc[i][2 + j], 0, 0, 0);
      }
    __builtin_amdgcn_s_setprio(0);
    __builtin_amdgcn_s_barrier();

#pragma unroll
    for (int i = 0; i < 4; i++) { a1[i][0] = rdA(cur, 4 + i, 0); a1[i][1] = rdA(cur, 4 + i, 1); }
    asm volatile("s_waitcnt lgkmcnt(4)" ::: "memory");
    __builtin_amdgcn_s_barrier();
    asm volatile("s_waitcnt lgkmcnt(0)" ::: "memory");
    __builtin_amdgcn_sched_barrier(0);
    __builtin_amdgcn_s_setprio(1);
#pragma unroll
    for (int i = 0; i < 4; i++)
#pragma unroll
      for (int j = 0; j < 2; j++) {
        acc[4 + i][2 + j] = __builtin_amdgcn_mfma_f32_16x16x32_bf16(a1[i][0], b23[j][0], acc[4 + i][2 + j], 0, 0, 0);
        acc[4 + i][2 + j] = __builtin_amdgcn_mfma_f32_16x16x32_bf16(a1[i][1], b23[j][1], acc[4 + i][2 + j], 0, 0, 0);
      }
    __builtin_amdgcn_s_setprio(0);
    __builtin_amdgcn_s_barrier();

    if (t + 2 < NT) { stgA(cur, t + 2, 0); stgA(cur, t + 2, 1); }
    __builtin_amdgcn_s_barrier();
    __builtin_amdgcn_sched_barrier(0);
    __builtin_amdgcn_s_setprio(1);
#pragma unroll
    for (int i = 0; i < 4; i++)
#pragma unroll
      for (int j = 0; j < 2; j++) {
        acc[4 + i][j] = __builtin_amdgcn_mfma_f32_16x16x32_bf16(a1[i][0], b01[j][0], acc[4 + i][j], 0, 0, 0);
        acc[4 + i][j] = __builtin_amdgcn_mfma_f32_16x16x32_bf16(a1[i][1], b01[j][1], acc[4 + i][j], 0, 0, 0);
      }
    __builtin_amdgcn_s_setprio(0);
    if (t + 2 < NT) asm volatile("s_waitcnt vmcnt(4)" ::: "memory");
    else            asm volatile("s_waitcnt vmcnt(0)" ::: "memory");
    __builtin_amdgcn_s_barrier();
  }

#pragma unroll
  for (int mi = 0; mi < 8; mi++) {
    const int row_base = m0 + wm * 128 + mi * 16 + kq * 4;
#pragma unroll
    for (int nj = 0; nj < 4; nj++) {
      const int col = n0 + wn * 64 + nj * 16 + ln;
#pragma unroll
      for (int r = 0; r < 4; r++) {
        const size_t idx = (size_t)(row_base + r) * N + col;
        if (COF32) ((float*)Cv)[idx] = acc[mi][nj][r];
        else       ((unsigned short*)Cv)[idx] = f2bf(acc[mi][nj][r]);
      }
    }
  }
}

// ---------------------------------------------------------------------------
// Transposed flash attention, 32x32x16 MFMA version.
// Block: 128 q rows, 4 waves (256 thr); wave w owns q cols q0+w*32+(lane&31).
// S^T = K Q^T: C/D col = q (lane&31), row = key (r&3)+8*(r>>2)+4*hi.
// P stays in registers (pack + shfl_xor(32) exchange) -> PV B-frags.
// K/V double-buffered, XOR-swizzled LDS; one barrier per tile.
// ---------------------------------------------------------------------------
#define TSEQ 2048
#define CDIM 2048
#define QKVLD 6144
#define DH 128
#define NEG_BIG (-1.0e30f)

__global__ __launch_bounds__(256, 2) void attn(
    const unsigned short* __restrict__ qkv,
    unsigned short* __restrict__ y) {
  __shared__ __align__(1024) unsigned short Klds[2][8192];  // [key][d] swz, 2x16KB
  __shared__ __align__(1024) unsigned short Vt[2][8192];    // [d][key] swz, 2x16KB

  const int tid  = threadIdx.x;
  const int lane = tid & 63;
  const int w    = tid >> 6;          // 0..3
  const int l5   = lane & 31;
  const int hi   = lane >> 5;

  // balanced decode (pairs sum to constant work across CUs)
  const int idx  = blockIdx.x;
  const int half = idx >> 8;
  const int qbi  = idx & 15;
  const int qb   = half ? qbi : 15 - qbi;
  const int h    = (idx >> 4) & 15;
  const int b    = half;
  const int q0   = qb * 128;
  const int qcol = q0 + w * 32 + l5;      // this lane's q row

  const size_t baseQ = (size_t)b * TSEQ * QKVLD + (size_t)h * DH;
  const size_t baseK = baseQ + CDIM;
  const size_t baseV = baseQ + 2 * CDIM;

  // Q B-frags: qf[c][j] = Q[d=c*16+hi*8+j][qcol], scaled by 1/sqrt(128)
  bf16x8 qf[8];
  {
    const float scale = 0.08838834764831845f;
    const unsigned short* qp = qkv + baseQ + (size_t)qcol * QKVLD + hi * 8;
#pragma unroll
    for (int c = 0; c < 8; c++) {
      u16x8 raw = *(const u16x8*)(qp + c * 16);
      u16x8 t;
#pragma unroll
      for (int j = 0; j < 8; j++) t[j] = f2bf(bf2f(raw[j]) * scale);
      qf[c] = __builtin_bit_cast(bf16x8, t);
    }
  }

  // --- staging geometry ---
  // K via global_load_lds: physical slot (key, s16) holds logical d-slot
  // s16 ^ (key&7); dest linear, source pre-swizzled per-lane.
  const int kkeyb = tid >> 4;            // + it*16
  const int kslot = tid & 15;
  // V^T reg staging: thread reads 4 keys x 8 d, writes swizzled u16x4 cols.
  const int vk4 = (tid & 15) * 4;
  const int vd8 = (tid >> 4) * 8;
  const unsigned short* Vgb = qkv + baseV + (size_t)vk4 * QKVLD + vd8;

  u16x8 vreg[4];

  auto stageK = [&](int buf, int kt) {
#pragma unroll
    for (int it = 0; it < 4; it++) {
      const int key = it * 16 + kkeyb;
      const unsigned short* src = qkv + baseK + (size_t)(kt * 64 + key) * QKVLD
                                + (size_t)((kslot ^ (key & 7)) * 8);
      gload16(src, (char*)&Klds[buf][0] + it * 4096 + w * 1024);
    }
  };
  auto loadV = [&](int kt) {
    const size_t off = (size_t)kt * 64 * QKVLD;
#pragma unroll
    for (int r = 0; r < 4; r++)
      vreg[r] = *(const u16x8*)(Vgb + off + (size_t)r * QKVLD);
  };
  auto writeV = [&](int buf) {
#pragma unroll
    for (int j = 0; j < 8; j++) {
      const int d = vd8 + j;
      u16x4 t4 = {vreg[0][j], vreg[1][j], vreg[2][j], vreg[3][j]};
      *(u16x4*)((char*)&Vt[buf][0] + d * 128 + ((vk4 * 2) ^ ((d & 7) << 4))) = t4;
    }
  };
  auto rdK = [&](int buf, int ks, int c) -> bf16x8 {
    const int key = ks * 32 + l5;
    return *(const bf16x8*)((const char*)&Klds[buf][0] + key * 256 +
                            ((c * 32 + hi * 16) ^ ((key & 7) << 4)));
  };
  auto rdV = [&](int buf, int ds, int kc) -> bf16x8 {
    const int d = ds * 32 + l5;
    return *(const bf16x8*)((const char*)&Vt[buf][0] + d * 128 +
                            ((kc * 32 + hi * 16) ^ ((d & 7) << 4)));
  };

  f32x16 o[4];
#pragma unroll
  for (int ds = 0; ds < 4; ds++)
#pragma unroll
    for (int r = 0; r < 16; r++) o[ds][r] = 0.f;
  float m = NEG_BIG, l = 0.f;

  const int ktEnd   = 2 * qb + 2;
  const int myKtMax = (q0 + w * 32) >> 6;   // wave-uniform

  // prologue: stage tile 0
  stageK(0, 0);
  loadV(0);
  writeV(0);
  __syncthreads();

  for (int kt = 0; kt < ktEnd; kt++) {
    const int buf = kt & 1;
    const bool pre = (kt + 1 < ktEnd);
    if (pre) { stageK(buf ^ 1, kt + 1); loadV(kt + 1); }

    if (kt <= myKtMax) {
      // --- S^T = K Q^T ---
      f32x16 s0, s1;
#pragma unroll
      for (int r = 0; r < 16; r++) { s0[r] = 0.f; s1[r] = 0.f; }
      __builtin_amdgcn_s_setprio(1);
#pragma unroll
      for (int c = 0; c < 8; c++) {
        bf16x8 k0 = rdK(buf, 0, c);
        bf16x8 k1 = rdK(buf, 1, c);
        s0 = __builtin_amdgcn_mfma_f32_32x32x16_bf16(k0, qf[c], s0, 0, 0, 0);
        s1 = __builtin_amdgcn_mfma_f32_32x32x16_bf16(k1, qf[c], s1, 0, 0, 0);
      }
      __builtin_amdgcn_s_setprio(0);

      // --- causal mask (diagonal tile only) ---
      if (kt == myKtMax) {
        const int kb0 = kt * 64 + 4 * hi;
#pragma unroll
        for (int r = 0; r < 16; r++) {
          const int row = (r & 3) + 8 * (r >> 2) + kb0;
          if (row > qcol)      s0[r] = NEG_BIG;
          if (row + 32 > qcol) s1[r] = NEG_BIG;
        }
      }

      // --- online softmax (lane owns q=qcol; partner lane^32 has other rows) ---
      float mt = s0[0];
#pragma unroll
      for (int r = 1; r < 16; r++) mt = fmaxf(mt, s0[r]);
#pragma unroll
      for (int r = 0; r < 16; r++) mt = fmaxf(mt, s1[r]);
      mt = fmaxf(mt, __shfl_xor(mt, 32, 64));

      const bool defer = __all(mt - m <= 8.0f);
      const float mn = defer ? m : fmaxf(m, mt);
      const float alpha = defer ? 1.0f : __expf(m - mn);
      m = mn;

      // p = exp(s-mn); pack own rows into bf16 pairs
      float ps = 0.f;
      unsigned int w0[2][4], w1[2][4];
#pragma unroll
      for (int g = 0; g < 4; g++) {
        float p0 = __expf(s0[4 * g + 0] - mn), p1 = __expf(s0[4 * g + 1] - mn);
        float p2 = __expf(s0[4 * g + 2] - mn), p3 = __expf(s0[4 * g + 3] - mn);
        ps += (p0 + p1) + (p2 + p3);
        w0[0][g] = (unsigned)f2bf(p0) | ((unsigned)f2bf(p1) << 16);
        w1[0][g] = (unsigned)f2bf(p2) | ((unsigned)f2bf(p3) << 16);
      }
#pragma unroll
      for (int g = 0; g < 4; g++) {
        float p0 = __expf(s1[4 * g + 0] - mn), p1 = __expf(s1[4 * g + 1] - mn);
        float p2 = __expf(s1[4 * g + 2] - mn), p3 = __expf(s1[4 * g + 3] - mn);
        ps += (p0 + p1) + (p2 + p3);
        w0[1][g] = (unsigned)f2bf(p0) | ((unsigned)f2bf(p1) << 16);
        w1[1][g] = (unsigned)f2bf(p2) | ((unsigned)f2bf(p3) << 16);
      }
      ps += __shfl_xor(ps, 32, 64);
      l = l * alpha + ps;

      if (!defer) {
#pragma unroll
        for (int ds = 0; ds < 4; ds++)
#pragma unroll
          for (int r = 0; r < 16; r++) o[ds][r] *= alpha;
      }

      // partner words; build PV B-frags in-register
      unsigned int pw0[2][4], pw1[2][4];
#pragma unroll
      for (int ks = 0; ks < 2; ks++)
#pragma unroll
        for (int g = 0; g < 4; g++) {
          pw0[ks][g] = (unsigned)__shfl_xor((int)w0[ks][g], 32, 64);
          pw1[ks][g] = (unsigned)__shfl_xor((int)w1[ks][g], 32, 64);
        }
      bf16x8 pf[4];
#pragma unroll
      for (int kc = 0; kc < 4; kc++) {
        const int ks = kc >> 1;
        const int g = ((kc & 1) << 1) | hi;
        u32x4v fw;
        fw[0] = hi ? pw0[ks][g] : w0[ks][g];
        fw[1] = hi ? pw1[ks][g] : w1[ks][g];
        fw[2] = hi ? w0[ks][g] : pw0[ks][g];
        fw[3] = hi ? w1[ks][g] : pw1[ks][g];
        pf[kc] = __builtin_bit_cast(bf16x8, fw);
      }

      // --- O^T += V^T P^T ---
      __builtin_amdgcn_s_setprio(1);
#pragma unroll
      for (int ds = 0; ds < 4; ds++)
#pragma unroll
        for (int kc = 0; kc < 4; kc++) {
          bf16x8 vf = rdV(buf, ds, kc);
          o[ds] = __builtin_amdgcn_mfma_f32_32x32x16_bf16(vf, pf[kc], o[ds], 0, 0, 0);
        }
      __builtin_amdgcn_s_setprio(0);
    }

    if (pre) writeV(buf ^ 1);   // vreg dependency waits handled by compiler
    __syncthreads();            // drains vmcnt (gload_lds) + lgkm before release
  }

  // --- epilogue: o[ds][r] = O[q=qcol][d = ds*32 + (r&3)+8*(r>>2)+4*hi] ---
  const float inv = 1.f / l;
  unsigned short* yp = y + (size_t)(b * TSEQ + qcol) * CDIM + (size_t)h * DH;
#pragma unroll
  for (int ds = 0; ds < 4; ds++)
#pragma unroll
    for (int g = 0; g < 4; g++) {
      u16x4 ov;
#pragma unroll
      for (int j = 0; j < 4; j++) ov[j] = f2bf(o[ds][4 * g + j] * inv);
      *(u16x4*)(yp + ds * 32 + 8 * g + 4 * hi) = ov;
    }
}

extern "C" void kernel_launch(void* const* d_in, const int* in_sizes, int n_in,
                              void* d_out, int out_size, void* d_ws, size_t ws_size,
                              hipStream_t stream) {
  const float* x     = (const float*)d_in[0];  // fp32 [4096][2048]
  const float* Wqkv  = (const float*)d_in[1];  // fp32 [6144][2048]
  const float* Wproj = (const float*)d_in[2];  // fp32 [2048][2048]
  void* out = d_out;                                   // fp32 [4096][2048]

  unsigned short* qkv = (unsigned short*)d_ws;         // bf16, 48MB
  unsigned short* y   = qkv + (size_t)4096 * 6144;     // bf16, 16MB (aliases x_bf)
  unsigned short* xbf = y;                             // x_bf dead before attn writes y
  unsigned short* wbf = y + (size_t)4096 * 2048;       // 24MB (Wqkv_bf, then Wproj_bf)

  f32_to_bf16<<<dim3(2048), 256, 0, stream>>>(x, xbf, (4096 * 2048) / 8);
  f32_to_bf16<<<dim3(2048), 256, 0, stream>>>(Wqkv, wbf, (6144 * 2048) / 8);
  gemm8<false><<<dim3(24, 16), 512, 0, stream>>>(xbf, wbf, qkv, 4096, 6144, 2048);
  f32_to_bf16<<<dim3(2048), 256, 0, stream>>>(Wproj, wbf, (2048 * 2048) / 8);  // Wqkv_bf dead
  attn<<<dim3(512), 256, 0, stream>>>(qkv, y);
  gemm_bf<true><<<dim3(16, 32), 256, 0, stream>>>(y, wbf, out, 4096, 2048, 2048);
}